// Round 1
// baseline (1188.425 us; speedup 1.0000x reference)
//
#include <hip/hip_runtime.h>
#include <math.h>

#define NB   64      // batch
#define GH   56      // spatial h=w
#define CC   96      // channels
#define NH   3       // heads
#define EE   32      // head dim
#define MM   7       // window size
#define WT   49      // tokens per window
#define C3   288     // 3*C
#define LL   3136    // tokens per image

// Kernel 1: per-(batch,window) fused qkv GEMM + window attention.
// Writes attention output in (B, L, C) layout (channel = head*32 + e) to ws.
__global__ __launch_bounds__(512) void swin_attn_kernel(
    const float* __restrict__ x,
    const float* __restrict__ w_qkv,
    const float* __restrict__ b_qkv,
    const float* __restrict__ rel_bias,
    float* __restrict__ attn_out)
{
    __shared__ float s_x[WT][CC];        // 18816 B
    __shared__ float s_w[CC][EE];        // 12288 B  (w_qkv column chunk)
    __shared__ float s_qkv[WT][CC + 1];  // 19012 B  (pad->97: 97%32==1, conflict-free strided reads)
    __shared__ float s_sc[WT][WT];       // 9604 B
    // total 59720 B < 64 KB -> 2 WG/CU

    const int tid = threadIdx.x;
    const int b   = blockIdx.x >> 6;
    const int win = blockIdx.x & 63;
    const int wy  = win >> 3;
    const int wx  = win & 7;

    // stage x window: token t -> global row (wy*7 + t/7)*56 + wx*7 + t%7
    for (int i = tid; i < WT * CC; i += 512) {
        int t = i / CC, c = i - t * CC;
        int row = (wy * MM + t / MM) * GH + wx * MM + (t % MM);
        s_x[t][c] = x[((size_t)b * LL + row) * CC + c];
    }
    __syncthreads();

    const float scale = 0.17677669529663687f;  // 1/sqrt(32)

    for (int hh = 0; hh < NH; ++hh) {
        // ---- qkv for this head (96 cols, layout col = e*3 + {q,k,v}), 3 chunks of 32 ----
        for (int cc = 0; cc < 3; ++cc) {
            for (int i = tid; i < CC * EE; i += 512) {
                int k = i >> 5, j = i & 31;
                s_w[k][j] = w_qkv[k * C3 + hh * CC + cc * EE + j];
            }
            __syncthreads();
            for (int i = tid; i < WT * EE; i += 512) {
                int t = i >> 5, j = i & 31;
                float a0 = 0.f, a1 = 0.f, a2 = 0.f, a3 = 0.f;
                #pragma unroll
                for (int k = 0; k < CC; k += 4) {
                    float4 xv = *(const float4*)&s_x[t][k];
                    a0 = fmaf(xv.x, s_w[k    ][j], a0);
                    a1 = fmaf(xv.y, s_w[k + 1][j], a1);
                    a2 = fmaf(xv.z, s_w[k + 2][j], a2);
                    a3 = fmaf(xv.w, s_w[k + 3][j], a3);
                }
                s_qkv[t][cc * EE + j] =
                    (a0 + a1) + (a2 + a3) + b_qkv[hh * CC + cc * EE + j];
            }
            __syncthreads();
        }

        // ---- scores = q.k * scale + rel_bias ----
        for (int i = tid; i < WT * WT; i += 512) {
            int qi = i / WT, ki = i - qi * WT;
            float a0 = 0.f, a1 = 0.f, a2 = 0.f, a3 = 0.f;
            #pragma unroll
            for (int e = 0; e < EE; e += 4) {
                a0 = fmaf(s_qkv[qi][3*e    ], s_qkv[ki][3*e + 1 ], a0);
                a1 = fmaf(s_qkv[qi][3*e + 3], s_qkv[ki][3*e + 4 ], a1);
                a2 = fmaf(s_qkv[qi][3*e + 6], s_qkv[ki][3*e + 7 ], a2);
                a3 = fmaf(s_qkv[qi][3*e + 9], s_qkv[ki][3*e + 10], a3);
            }
            s_sc[qi][ki] = ((a0 + a1) + (a2 + a3)) * scale + rel_bias[i];
        }
        __syncthreads();

        // ---- softmax over rows (49 threads) ----
        if (tid < WT) {
            float mx = -1e30f;
            for (int j = 0; j < WT; ++j) mx = fmaxf(mx, s_sc[tid][j]);
            float sum = 0.f;
            for (int j = 0; j < WT; ++j) {
                float ev = __expf(s_sc[tid][j] - mx);
                s_sc[tid][j] = ev;
                sum += ev;
            }
            float inv = 1.0f / sum;
            for (int j = 0; j < WT; ++j) s_sc[tid][j] *= inv;
        }
        __syncthreads();

        // ---- out = attn @ v -> global (B, L, C) with channel = hh*32 + e ----
        for (int i = tid; i < WT * EE; i += 512) {
            int qi = i >> 5, e = i & 31;
            float a0 = 0.f, a1 = 0.f, a2 = 0.f, a3 = 0.f;
            #pragma unroll
            for (int k = 0; k < 48; k += 4) {
                a0 = fmaf(s_sc[qi][k    ], s_qkv[k    ][3*e + 2], a0);
                a1 = fmaf(s_sc[qi][k + 1], s_qkv[k + 1][3*e + 2], a1);
                a2 = fmaf(s_sc[qi][k + 2], s_qkv[k + 2][3*e + 2], a2);
                a3 = fmaf(s_sc[qi][k + 3], s_qkv[k + 3][3*e + 2], a3);
            }
            float a = (a0 + a1) + (a2 + a3) + s_sc[qi][48] * s_qkv[48][3*e + 2];
            int row = (wy * MM + qi / MM) * GH + wx * MM + (qi % MM);
            attn_out[((size_t)b * LL + row) * CC + hh * EE + e] = a;
        }
        __syncthreads();
    }
}

// Kernel 2: out = A @ w_proj + b_proj, A = attention output (200704 x 96)
__global__ __launch_bounds__(512) void proj_kernel(
    const float* __restrict__ A,
    const float* __restrict__ W,
    const float* __restrict__ bias,
    float* __restrict__ out)
{
    __shared__ float s_a[64][CC];   // 24576 B
    __shared__ float s_w[CC][CC];   // 36864 B  -> total 61440 B < 64 KB
    const int tid = threadIdx.x;
    const size_t r0 = (size_t)blockIdx.x * 64;

    for (int i = tid; i < CC * CC; i += 512) s_w[i / CC][i % CC] = W[i];
    for (int i = tid; i < 64 * CC; i += 512) s_a[i / CC][i % CC] = A[r0 * CC + i];
    __syncthreads();

    for (int i = tid; i < 64 * CC; i += 512) {
        int r = i / CC, c = i - (i / CC) * CC;
        float a0 = 0.f, a1 = 0.f, a2 = 0.f, a3 = 0.f;
        #pragma unroll
        for (int k = 0; k < CC; k += 4) {
            float4 av = *(const float4*)&s_a[r][k];
            a0 = fmaf(av.x, s_w[k    ][c], a0);
            a1 = fmaf(av.y, s_w[k + 1][c], a1);
            a2 = fmaf(av.z, s_w[k + 2][c], a2);
            a3 = fmaf(av.w, s_w[k + 3][c], a3);
        }
        out[r0 * CC + i] = (a0 + a1) + (a2 + a3) + bias[c];
    }
}

extern "C" void kernel_launch(void* const* d_in, const int* in_sizes, int n_in,
                              void* d_out, int out_size, void* d_ws, size_t ws_size,
                              hipStream_t stream)
{
    const float* x        = (const float*)d_in[0];
    const float* w_qkv    = (const float*)d_in[1];
    const float* b_qkv    = (const float*)d_in[2];
    const float* w_proj   = (const float*)d_in[3];
    const float* b_proj   = (const float*)d_in[4];
    const float* rel_bias = (const float*)d_in[5];
    float* out  = (float*)d_out;
    float* attn = (float*)d_ws;   // needs 64*3136*96*4 = 77,070,336 B of ws

    swin_attn_kernel<<<dim3(NB * 64), dim3(512), 0, stream>>>(
        x, w_qkv, b_qkv, rel_bias, attn);
    proj_kernel<<<dim3(LL * NB / 64), dim3(512), 0, stream>>>(
        attn, w_proj, b_proj, out);
}

// Round 2
// 272.477 us; speedup vs baseline: 4.3616x; 4.3616x over previous
//
#include <hip/hip_runtime.h>

typedef unsigned int u32;
typedef __bf16 bf16_t;
typedef bf16_t bf16x8 __attribute__((ext_vector_type(8)));
typedef float f32x4 __attribute__((ext_vector_type(4)));

#define NB 64
#define GH 56
#define CC 96
#define NH 3
#define MM 7
#define WT 49
#define C3 288
#define LL 3136

// ws layout (bytes)
static constexpr size_t ATTN_OFF = 0;                          // bf16 [NB*LL][CC] = 38,535,168 B
static constexpr size_t WQ_OFF   = (size_t)NB * LL * CC * 2;   // 54 frags * 1024 B
static constexpr size_t WP_OFF   = WQ_OFF + 54 * 1024;         // 18 frags * 1024 B
static constexpr size_t BR_OFF   = WP_OFF + 18 * 1024;         // 288 floats

static __device__ __forceinline__ unsigned short f2bu(float f) {
    union { bf16_t b; unsigned short u; } c; c.b = (bf16_t)f; return c.u;
}
static __device__ __forceinline__ f32x4 mfma16(bf16x8 a, bf16x8 b, f32x4 c) {
    return __builtin_amdgcn_mfma_f32_16x16x32_bf16(a, b, c, 0, 0, 0);
}

// ---------------------------------------------------------------------------
// prep: w_qkv / w_proj -> bf16 B-fragment layout; b_qkv de-interleave.
// B-frag for (nt, ks): lane l, elem j = B[32*ks + 8*(l>>4) + j][16*nt + (l&15)]
// qkv col' = which*32 + e  <->  w_qkv col = h*96 + e*3 + which
// ---------------------------------------------------------------------------
__global__ __launch_bounds__(64) void prep_kernel(
    const float* __restrict__ w_qkv, const float* __restrict__ b_qkv,
    const float* __restrict__ w_proj, char* __restrict__ ws)
{
    const int l = threadIdx.x;
    const int blk = blockIdx.x;
    if (blk < 54) {
        const int h = blk / 18, nt = (blk % 18) / 3, ks = blk % 3;
        const int colp = nt * 16 + (l & 15);
        const int e = colp & 31, wh = colp >> 5;
        const int k0 = ks * 32 + (l >> 4) * 8;
        u32 p[4];
        #pragma unroll
        for (int jj = 0; jj < 4; ++jj) {
            unsigned short a = f2bu(w_qkv[(size_t)(k0 + 2*jj    ) * C3 + h * CC + e * 3 + wh]);
            unsigned short b = f2bu(w_qkv[(size_t)(k0 + 2*jj + 1) * C3 + h * CC + e * 3 + wh]);
            p[jj] = (u32)a | ((u32)b << 16);
        }
        uint4 v; v.x = p[0]; v.y = p[1]; v.z = p[2]; v.w = p[3];
        *(uint4*)(ws + WQ_OFF + ((size_t)blk * 64 + l) * 16) = v;
    } else if (blk < 72) {
        const int idx = blk - 54, nt = idx / 3, ks = idx % 3;
        const int n = nt * 16 + (l & 15);
        const int k0 = ks * 32 + (l >> 4) * 8;
        u32 p[4];
        #pragma unroll
        for (int jj = 0; jj < 4; ++jj) {
            unsigned short a = f2bu(w_proj[(size_t)(k0 + 2*jj    ) * CC + n]);
            unsigned short b = f2bu(w_proj[(size_t)(k0 + 2*jj + 1) * CC + n]);
            p[jj] = (u32)a | ((u32)b << 16);
        }
        uint4 v; v.x = p[0]; v.y = p[1]; v.z = p[2]; v.w = p[3];
        *(uint4*)(ws + WP_OFF + ((size_t)idx * 64 + l) * 16) = v;
    } else {
        float* br = (float*)(ws + BR_OFF);
        for (int i = l; i < C3; i += 64) {
            int h = i / CC, c = i % CC;
            br[i] = b_qkv[h * CC + (c & 31) * 3 + (c >> 5)];
        }
    }
}

// ---------------------------------------------------------------------------
// attn: one block per (batch, window); 4 waves, wave w owns m-tile w (16 rows).
// ---------------------------------------------------------------------------
__global__ __launch_bounds__(256, 3) void attn_kernel(
    const float* __restrict__ x, const float* __restrict__ rel_bias,
    const char* __restrict__ wsro, bf16_t* __restrict__ attn_out)
{
    __shared__ bf16_t s_x [64][104];  // stride 208 B (16-aligned, 2-way banks)
    __shared__ bf16_t s_q [64][40];   // stride 80 B
    __shared__ bf16_t s_k [64][40];
    __shared__ bf16_t s_vT[32][72];   // V transposed [e][token], stride 144 B
    __shared__ bf16_t s_p [64][72];   // P [q][k], stride 144 B
    __shared__ float  s_bias[WT][50];
    // total 47,176 B -> 3 blocks/CU

    const int tid = threadIdx.x;
    const int l = tid & 63, w = tid >> 6;
    const int ln = l & 15, quad = l >> 4;
    const int b = blockIdx.x >> 6, win = blockIdx.x & 63;
    const int wy = win >> 3, wx = win & 7;
    const int q0 = 16 * w + quad * 4;

    // stage x window fp32 -> bf16 (rows >= 49 zeroed to keep padding clean)
    for (int i = tid; i < 1536; i += 256) {
        const int t = i / 24, c4 = (i % 24) * 4;
        float4 xv = {0.f, 0.f, 0.f, 0.f};
        if (t < WT) {
            const int grow = (wy * MM + t / MM) * GH + wx * MM + t % MM;
            xv = *(const float4*)&x[((size_t)b * LL + grow) * CC + c4];
        }
        ushort4 pv;
        pv.x = f2bu(xv.x); pv.y = f2bu(xv.y); pv.z = f2bu(xv.z); pv.w = f2bu(xv.w);
        *(ushort4*)((char*)&s_x[0][0] + t * 208 + c4 * 2) = pv;
    }
    for (int i = tid; i < WT * WT; i += 256) s_bias[i / WT][i % WT] = rel_bias[i];
    __syncthreads();

    const char* wq = wsro + WQ_OFF;
    const float* br = (const float*)(wsro + BR_OFF);
    const float scale = 0.17677669529663687f;  // 1/sqrt(32)

    for (int h = 0; h < NH; ++h) {
        // ---- qkv GEMM: wave computes rows 16w..16w+15, all 96 cols ----
        const char* sxrow = (const char*)&s_x[0][0] + (16 * w + ln) * 208 + quad * 16;
        bf16x8 a0 = *(const bf16x8*)(sxrow);
        bf16x8 a1 = *(const bf16x8*)(sxrow + 64);
        bf16x8 a2 = *(const bf16x8*)(sxrow + 128);
        #pragma unroll
        for (int nt = 0; nt < 6; ++nt) {
            const char* wqp = wq + ((size_t)(h * 18 + nt * 3)) * 1024 + (size_t)l * 16;
            bf16x8 b0 = *(const bf16x8*)(wqp);
            bf16x8 b1 = *(const bf16x8*)(wqp + 1024);
            bf16x8 b2 = *(const bf16x8*)(wqp + 2048);
            f32x4 acc = {0.f, 0.f, 0.f, 0.f};
            acc = mfma16(a0, b0, acc);
            acc = mfma16(a1, b1, acc);
            acc = mfma16(a2, b2, acc);
            const float bias = br[h * CC + nt * 16 + ln];
            if (nt < 4) {  // q (nt 0,1) / k (nt 2,3): row-major [t][e]
                bf16_t* dst = (nt < 2) ? &s_q[0][0] : &s_k[0][0];
                const int col = (nt & 1) * 16 + ln;
                #pragma unroll
                for (int r = 0; r < 4; ++r) {
                    float v = acc[r] + bias;
                    float ov = __shfl_xor(v, 1);
                    if (!(l & 1))
                        *(u32*)((char*)dst + (q0 + r) * 80 + col * 2) =
                            (u32)f2bu(v) | ((u32)f2bu(ov) << 16);
                }
            } else {       // v: transposed [e][t] -> lane's 4 rows contiguous
                const int e = (nt - 4) * 16 + ln;
                uint2 pk;
                pk.x = (u32)f2bu(acc[0] + bias) | ((u32)f2bu(acc[1] + bias) << 16);
                pk.y = (u32)f2bu(acc[2] + bias) | ((u32)f2bu(acc[3] + bias) << 16);
                *(uint2*)((char*)&s_vT[0][0] + e * 144 + q0 * 2) = pk;
            }
        }
        __syncthreads();

        // ---- S = Q K^T * scale + bias; masked softmax ----
        bf16x8 qa = *(const bf16x8*)((const char*)&s_q[0][0] + (16 * w + ln) * 80 + quad * 16);
        float sv[4][4];
        #pragma unroll
        for (int nt = 0; nt < 4; ++nt) {
            bf16x8 kb = *(const bf16x8*)((const char*)&s_k[0][0] + (16 * nt + ln) * 80 + quad * 16);
            f32x4 z = {0.f, 0.f, 0.f, 0.f};
            z = mfma16(qa, kb, z);
            const int kk = 16 * nt + ln;
            #pragma unroll
            for (int r = 0; r < 4; ++r) {
                const int q = q0 + r;
                float bb = (q < WT && kk < WT) ? s_bias[q][kk] : 0.f;
                float v = z[r] * scale + bb;
                sv[nt][r] = (kk < WT) ? v : -1e30f;
            }
        }
        #pragma unroll
        for (int r = 0; r < 4; ++r) {
            float m = fmaxf(fmaxf(sv[0][r], sv[1][r]), fmaxf(sv[2][r], sv[3][r]));
            m = fmaxf(m, __shfl_xor(m, 1));
            m = fmaxf(m, __shfl_xor(m, 2));
            m = fmaxf(m, __shfl_xor(m, 4));
            m = fmaxf(m, __shfl_xor(m, 8));
            float s = 0.f;
            #pragma unroll
            for (int nt = 0; nt < 4; ++nt) { sv[nt][r] = __expf(sv[nt][r] - m); s += sv[nt][r]; }
            s += __shfl_xor(s, 1);
            s += __shfl_xor(s, 2);
            s += __shfl_xor(s, 4);
            s += __shfl_xor(s, 8);
            const float inv = 1.f / s;
            #pragma unroll
            for (int nt = 0; nt < 4; ++nt) sv[nt][r] *= inv;
        }
        #pragma unroll
        for (int nt = 0; nt < 4; ++nt) {
            const int kk = 16 * nt + ln;
            #pragma unroll
            for (int r = 0; r < 4; ++r) {
                float v = sv[nt][r];
                float ov = __shfl_xor(v, 1);
                if (!(l & 1))
                    *(u32*)((char*)&s_p[0][0] + (q0 + r) * 144 + kk * 2) =
                        (u32)f2bu(v) | ((u32)f2bu(ov) << 16);
            }
        }
        __syncthreads();

        // ---- O = P V ; write bf16 to ws in (B, L, C) layout ----
        const char* sprow = (const char*)&s_p[0][0] + (16 * w + ln) * 144 + quad * 16;
        bf16x8 pa0 = *(const bf16x8*)(sprow);
        bf16x8 pa1 = *(const bf16x8*)(sprow + 64);
        #pragma unroll
        for (int nt = 0; nt < 2; ++nt) {
            const char* svr = (const char*)&s_vT[0][0] + (16 * nt + ln) * 144 + quad * 16;
            bf16x8 vb0 = *(const bf16x8*)(svr);
            bf16x8 vb1 = *(const bf16x8*)(svr + 64);
            f32x4 z = {0.f, 0.f, 0.f, 0.f};
            z = mfma16(pa0, vb0, z);
            z = mfma16(pa1, vb1, z);
            const int c = h * 32 + nt * 16 + ln;
            #pragma unroll
            for (int r = 0; r < 4; ++r) {
                const int t = q0 + r;
                float v = z[r];
                float ov = __shfl_xor(v, 1);
                if (!(l & 1) && t < WT) {
                    const int grow = (wy * MM + t / MM) * GH + wx * MM + t % MM;
                    const size_t off = ((size_t)b * LL + grow) * CC + c;
                    *(u32*)((char*)attn_out + off * 2) = (u32)f2bu(v) | ((u32)f2bu(ov) << 16);
                }
            }
        }
        __syncthreads();
    }
}

// ---------------------------------------------------------------------------
// proj: out = attn(bf16) @ w_proj + b_proj, 128 rows/block, MFMA
// ---------------------------------------------------------------------------
__global__ __launch_bounds__(256) void proj_kernel(
    const bf16_t* __restrict__ A, const char* __restrict__ wsro,
    const float* __restrict__ b_proj, float* __restrict__ out)
{
    __shared__ bf16_t s_a[128][104];  // 26,624 B
    const int tid = threadIdx.x;
    const int l = tid & 63, w = tid >> 6;
    const int ln = l & 15, quad = l >> 4;
    const size_t r0 = (size_t)blockIdx.x * 128;

    for (int i = tid; i < 1536; i += 256) {
        const int row = i / 12, c8 = (i % 12) * 8;
        uint4 v = *(const uint4*)((const char*)A + ((r0 + row) * CC + c8) * 2);
        *(uint4*)((char*)&s_a[0][0] + row * 208 + c8 * 2) = v;
    }
    __syncthreads();

    const char* wp = wsro + WP_OFF;
    bf16x8 af[2][3];
    #pragma unroll
    for (int m2 = 0; m2 < 2; ++m2) {
        const char* sar = (const char*)&s_a[0][0] + (16 * (2 * w + m2) + ln) * 208 + quad * 16;
        af[m2][0] = *(const bf16x8*)(sar);
        af[m2][1] = *(const bf16x8*)(sar + 64);
        af[m2][2] = *(const bf16x8*)(sar + 128);
    }
    #pragma unroll
    for (int nt = 0; nt < 6; ++nt) {
        const char* wpp = wp + (size_t)(nt * 3) * 1024 + (size_t)l * 16;
        bf16x8 b0 = *(const bf16x8*)(wpp);
        bf16x8 b1 = *(const bf16x8*)(wpp + 1024);
        bf16x8 b2 = *(const bf16x8*)(wpp + 2048);
        const float bias = b_proj[nt * 16 + ln];
        #pragma unroll
        for (int m2 = 0; m2 < 2; ++m2) {
            f32x4 acc = {0.f, 0.f, 0.f, 0.f};
            acc = mfma16(af[m2][0], b0, acc);
            acc = mfma16(af[m2][1], b1, acc);
            acc = mfma16(af[m2][2], b2, acc);
            const size_t row0 = r0 + 16 * (2 * w + m2) + quad * 4;
            #pragma unroll
            for (int r = 0; r < 4; ++r)
                out[(row0 + r) * CC + nt * 16 + ln] = acc[r] + bias;
        }
    }
}

extern "C" void kernel_launch(void* const* d_in, const int* in_sizes, int n_in,
                              void* d_out, int out_size, void* d_ws, size_t ws_size,
                              hipStream_t stream)
{
    const float* x      = (const float*)d_in[0];
    const float* w_qkv  = (const float*)d_in[1];
    const float* b_qkv  = (const float*)d_in[2];
    const float* w_proj = (const float*)d_in[3];
    const float* b_proj = (const float*)d_in[4];
    const float* rb     = (const float*)d_in[5];
    char* ws = (char*)d_ws;

    prep_kernel<<<73, 64, 0, stream>>>(w_qkv, b_qkv, w_proj, ws);
    attn_kernel<<<NB * 64, 256, 0, stream>>>(x, rb, ws, (bf16_t*)(ws + ATTN_OFF));
    proj_kernel<<<(NB * LL) / 128, 256, 0, stream>>>(
        (const bf16_t*)(ws + ATTN_OFF), ws, b_proj, (float*)d_out);
}